// Round 3
// baseline (142.803 us; speedup 1.0000x reference)
//
#include <hip/hip_runtime.h>
#include <math.h>

// Distral per-task MLP: 32769 heads, h = relu(W1[3->100] x + b1),
// p = softmax(W2[100->5] h + b2).  ~3.6 KB read/head, ~119 MB total.
//
// R3: kill the LDS-pipe bottleneck.
//  - W1|b1 staged via global_load_lds dwordx4 (wave-private region).
//  - W2, x, b2 loaded straight into registers: 10+8 independent coalesced
//    dword loads issued back-to-back -> batched latency, no LDS round-trip.
//  - One per-wave s_waitcnt vmcnt(0) (no __syncthreads: regions are private).
//  - Logit reduction via DPP v_add chain (VALU pipe) instead of 30
//    ds_swizzle ops on the LDS pipe; result read uniformly from lane 63.

#define N_HEADS 32769
#define HID     100
#define OUT     5

#define HEADS_PER_BLOCK 4            // 4 waves x 64 lanes = 256 threads
#define FLOATS_PER_HEAD 400          // W1 300 | b1 100
#define LDS_B1 300

#define GLOBAL_AS __attribute__((address_space(1)))
#define LDS_AS    __attribute__((address_space(3)))

static __device__ __forceinline__ void async_copy16(const void* g, void* l) {
    __builtin_amdgcn_global_load_lds((const GLOBAL_AS void*)g, (LDS_AS void*)l,
                                     16, 0, 0);
}

// one step of LLVM's canonical wave64 DPP reduction: acc += dpp(acc)
template <int CTRL, int ROW_MASK>
static __device__ __forceinline__ float dpp_add_step(float acc) {
    union { float f; int i; } in, out;
    in.f = acc;
    out.i = __builtin_amdgcn_update_dpp(0, in.i, CTRL, ROW_MASK, 0xF, false);
    return acc + out.f;
}

static __device__ __forceinline__ float wave_reduce_add(float acc) {
    acc = dpp_add_step<0x111, 0xF>(acc);  // row_shr:1
    acc = dpp_add_step<0x112, 0xF>(acc);  // row_shr:2
    acc = dpp_add_step<0x114, 0xF>(acc);  // row_shr:4
    acc = dpp_add_step<0x118, 0xF>(acc);  // row_shr:8   (lane15 of each row = row sum)
    acc = dpp_add_step<0x142, 0xA>(acc);  // row_bcast:15 -> rows 1,3
    acc = dpp_add_step<0x143, 0xC>(acc);  // row_bcast:31 -> rows 2,3 (lane63 = total)
    union { float f; int i; } v, r;
    v.f = acc;
    r.i = __builtin_amdgcn_readlane(v.i, 63);  // wave-uniform total
    return r.f;
}

__global__ __launch_bounds__(256) void distral_kernel(
    const float* __restrict__ x,
    const float* __restrict__ W1,
    const float* __restrict__ b1,
    const float* __restrict__ W2,
    const float* __restrict__ b2,
    float* __restrict__ out)
{
    __shared__ float lds[HEADS_PER_BLOCK * FLOATS_PER_HEAD];   // 6400 B

    const int wave = threadIdx.x >> 6;
    const int lane = threadIdx.x & 63;
    const int head = blockIdx.x * HEADS_PER_BLOCK + wave;
    if (head >= N_HEADS) return;           // wave-uniform: exec stays full-64

    float* region = lds + wave * FLOATS_PER_HEAD;

    // ---- issue the W1|b1 DMA first (bulk of the bytes) ----
    const float* W1h = W1 + (size_t)head * 300;
    const float* b1h = b1 + (size_t)head * 100;
    async_copy16(W1h + 4 * lane,           region);            // f4 0..63
    if (lane < 11)
        async_copy16(W1h + 256 + 4 * lane, region + 256);      // f4 64..74
    if (lane < 25)
        async_copy16(b1h + 4 * lane,       region + LDS_B1);   // b1: 25 f4

    // ---- W2 / x / b2 straight into registers while DMA is in flight ----
    const float* W2h = W2 + (size_t)head * 500;
    const bool has2 = (lane < HID - 64);   // lanes 0..35 own h[lane+64]

    float w2a[OUT], w2b[OUT] = {0.f, 0.f, 0.f, 0.f, 0.f};
#pragma unroll
    for (int o = 0; o < OUT; ++o)
        w2a[o] = W2h[o * HID + lane];              // 64 consecutive: coalesced
    if (has2) {
#pragma unroll
        for (int o = 0; o < OUT; ++o)
            w2b[o] = W2h[o * HID + 64 + lane];     // 36-float tail
    }

    const float x0 = x[head * 3 + 0];
    const float x1 = x[head * 3 + 1];
    const float x2 = x[head * 3 + 2];
    float b2v[OUT];
#pragma unroll
    for (int o = 0; o < OUT; ++o) b2v[o] = b2[head * OUT + o];

    // ---- single per-wave drain of the LDS-DMA (region is wave-private) ----
    __builtin_amdgcn_s_waitcnt(0x0F70);    // vmcnt(0), expcnt/lgkmcnt untouched
    asm volatile("" ::: "memory");         // keep ds_reads below the wait

    // ---- layer 1 from LDS: lane computes h[lane] and h[lane+64] ----
    float h0, h1 = 0.0f;
    {
        const float* r = region + 3 * lane;
        h0 = fmaxf(fmaf(r[0], x0, fmaf(r[1], x1, fmaf(r[2], x2,
                   region[LDS_B1 + lane]))), 0.0f);
    }
    if (has2) {
        const float* r = region + 3 * (lane + 64);
        h1 = fmaxf(fmaf(r[0], x0, fmaf(r[1], x1, fmaf(r[2], x2,
                   region[LDS_B1 + lane + 64]))), 0.0f);
    }

    // ---- layer 2 entirely in registers ----
    float logit[OUT];
#pragma unroll
    for (int o = 0; o < OUT; ++o) {
        float p = fmaf(w2b[o], h1, w2a[o] * h0);   // w2b==0 when !has2
        logit[o] = wave_reduce_add(p) + b2v[o];    // VALU DPP chain, uniform result
    }

    // ---- softmax on 5 wave-uniform scalars ----
    float m = -INFINITY;
#pragma unroll
    for (int o = 0; o < OUT; ++o) m = fmaxf(m, logit[o]);
    float e[OUT], s = 0.0f;
#pragma unroll
    for (int o = 0; o < OUT; ++o) { e[o] = __expf(logit[o] - m); s += e[o]; }
    const float inv = 1.0f / s;

    if (lane < OUT) {
        float v = (lane == 0) ? e[0]
                : (lane == 1) ? e[1]
                : (lane == 2) ? e[2]
                : (lane == 3) ? e[3]
                :               e[4];
        out[(size_t)head * OUT + lane] = v * inv;
    }
}

extern "C" void kernel_launch(void* const* d_in, const int* in_sizes, int n_in,
                              void* d_out, int out_size, void* d_ws, size_t ws_size,
                              hipStream_t stream) {
    const float* x  = (const float*)d_in[0];
    const float* W1 = (const float*)d_in[1];
    const float* b1 = (const float*)d_in[2];
    const float* W2 = (const float*)d_in[3];
    const float* b2 = (const float*)d_in[4];
    float* out = (float*)d_out;

    const int blocks = (N_HEADS + HEADS_PER_BLOCK - 1) / HEADS_PER_BLOCK;
    distral_kernel<<<blocks, 256, 0, stream>>>(x, W1, b1, W2, b2, out);
}